// Round 7
// baseline (851.180 us; speedup 1.0000x reference)
//
#include <hip/hip_runtime.h>

#define NN 50000
#define NE 800000
#define DIN 256
#define DOUT 256
#define NSLICE 8
#define SLICE_COLS 32
#define CHUNK_NODES 64
#define NCHUNK ((NN + CHUNK_NODES - 1) / CHUNK_NODES)  // 782

typedef __attribute__((ext_vector_type(8))) short short8;
typedef __attribute__((ext_vector_type(4))) float floatx4;

static __device__ __forceinline__ unsigned short f2bf(float f) {
    unsigned int u = __float_as_uint(f);
    unsigned int r = (u + 0x7fffu + ((u >> 16) & 1u)) >> 16;
    return (unsigned short)r;
}
static __device__ __forceinline__ float bf2f(unsigned short h) {
    return __uint_as_float(((unsigned int)h) << 16);
}

static __device__ __forceinline__ void gload_lds16(const void* g, void* l) {
    __builtin_amdgcn_global_load_lds(
        (const __attribute__((address_space(1))) unsigned int*)g,
        (__attribute__((address_space(3))) unsigned int*)l, 16, 0, 0);
}

static __device__ __forceinline__ void nt_store8(short8 v, unsigned short* p) {
    __builtin_nontemporal_store(v, (short8*)p);
}

// ---------------- utility: zero ints ----------------
__global__ void zero_ints_kernel(int* __restrict__ p, int n) {
    int i = blockIdx.x * blockDim.x + threadIdx.x;
    if (i < n) p[i] = 0;
}

// ---- fused prep: cast x -> SLICED bf16 slabs, cast+transpose W, degree hist ----
// xbs layout: slab s (cols [32s,32s+32)) is contiguous: xbs[s*NN*32 + node*32 + c]
__global__ __launch_bounds__(256) void prep_kernel(const float* __restrict__ x,
                                                   const float* __restrict__ W,
                                                   unsigned short* __restrict__ xbs,
                                                   unsigned short* __restrict__ Wt,
                                                   const int* __restrict__ edst,
                                                   int* __restrict__ deg) {
    int bid = blockIdx.x;
    if (bid < 2048) {
        const int total = NN * 32;  // 8-col groups
        int stride = 2048 * 256;
        for (int i = bid * 256 + threadIdx.x; i < total; i += stride) {
            int node = i >> 5, cg = i & 31;
            const float* src = x + (size_t)node * DIN + cg * 8;
            float4 v0 = *(const float4*)(src);
            float4 v1 = *(const float4*)(src + 4);
            short8 o;
            o[0] = (short)f2bf(v0.x); o[1] = (short)f2bf(v0.y);
            o[2] = (short)f2bf(v0.z); o[3] = (short)f2bf(v0.w);
            o[4] = (short)f2bf(v1.x); o[5] = (short)f2bf(v1.y);
            o[6] = (short)f2bf(v1.z); o[7] = (short)f2bf(v1.w);
            int s = cg >> 2;
            int c8 = (cg & 3) * 8;
            nt_store8(o, xbs + (size_t)s * NN * SLICE_COLS + (size_t)node * SLICE_COLS + c8);
        }
    } else if (bid < 2304) {
        int n = bid - 2048;
        int k = threadIdx.x;
        Wt[(size_t)n * DIN + k] = f2bf(W[(size_t)k * DOUT + n]);
    } else {
        int stride = 2048 * 256;
        for (int e = (bid - 2304) * 256 + threadIdx.x; e < NE; e += stride)
            atomicAdd(&deg[edst[e]], 1);
    }
}

// ---------------- single-block exclusive scan over 50000 ints ----------------
__global__ __launch_bounds__(1024) void scan_kernel(const int* __restrict__ deg,
                                                    int* __restrict__ offs) {
    __shared__ int bufA[1024];
    __shared__ int bufB[1024];
    int t = threadIdx.x;
    const int chunk = (NN + 1023) / 1024;  // 49
    int begin = t * chunk;
    int end = begin + chunk;
    if (begin > NN) begin = NN;
    if (end > NN) end = NN;
    int s = 0;
    for (int i = begin; i < end; i++) s += deg[i];
    bufA[t] = s;
    __syncthreads();
    int* src = bufA;
    int* dst = bufB;
    for (int off = 1; off < 1024; off <<= 1) {
        dst[t] = src[t] + ((t >= off) ? src[t - off] : 0);
        __syncthreads();
        int* tmp = src; src = dst; dst = tmp;
    }
    int run = (t == 0) ? 0 : src[t - 1];
    for (int i = begin; i < end; i++) { offs[i] = run; run += deg[i]; }
    if (t == 1023) offs[NN] = src[1023];  // == NE
}

// ---------------- scatter edges into CSR (by destination) ----------------
__global__ void scatter_kernel(const int* __restrict__ edge_src,
                               const int* __restrict__ edge_dst,
                               const int* __restrict__ offs,
                               int* __restrict__ cursor,
                               int* __restrict__ sorted_src) {
    int stride = gridDim.x * blockDim.x;
    for (int e = blockIdx.x * blockDim.x + threadIdx.x; e < NE; e += stride) {
        int d = edge_dst[e];
        int pos = offs[d] + atomicAdd(&cursor[d], 1);
        sorted_src[pos] = edge_src[e];
    }
}

// ---------------- XCD-sliced per-node mean: xbs slabs -> xm (bf16 row-major) ---
// Each block reads its REAL XCD id (s_getreg HW_REG_XCC_ID) and drains the
// chunk queue of slice == xcd (slab 3.2 MB -> L2-resident per XCD), then
// falls back to other slices' queues (correct under any block->XCD mapping).
// Per chunk: 64 nodes; 4 lanes/node; lane q takes edges beg+q, +4, ... and
// accumulates all 32 slab cols in regs; quad-combine via shfl_xor(1,2);
// lane q writes cols [q*8,q*8+8) of the slice with a non-temporal store.
__global__ __launch_bounds__(256) void slice_mean_kernel(const unsigned short* __restrict__ xbs,
                                                         const int* __restrict__ offs,
                                                         const int* __restrict__ ss,
                                                         int* __restrict__ sctr,
                                                         unsigned short* __restrict__ xm) {
    __shared__ int cur;
    int xcd;
    asm("s_getreg_b32 %0, hwreg(HW_REG_XCC_ID, 0, 32)" : "=s"(xcd));
    xcd &= 7;
    int tid = threadIdx.x;
    int nq = tid >> 2;  // node 0..63 within chunk
    int q = tid & 3;    // quad lane

    for (int t = 0; t < NSLICE; t++) {
        int s = (xcd + t) & 7;
        const unsigned short* slab = xbs + (size_t)s * NN * SLICE_COLS;
        while (true) {
            if (tid == 0) cur = atomicAdd(&sctr[s], 1);
            __syncthreads();
            int chunk = cur;
            __syncthreads();
            if (chunk >= NCHUNK) break;
            int node = chunk * CHUNK_NODES + nq;
            if (node < NN) {
                int beg = offs[node], end = offs[node + 1];
                float a[32];
#pragma unroll
                for (int j = 0; j < 32; j++) a[j] = 0.f;
                int i = beg + q;
                for (; i + 4 < end; i += 8) {  // 2 edges per iter for this lane
                    int s0 = ss[i], s1 = ss[i + 4];
                    const unsigned short* p0 = slab + (size_t)s0 * SLICE_COLS;
                    const unsigned short* p1 = slab + (size_t)s1 * SLICE_COLS;
                    short8 v00 = *(const short8*)(p0);
                    short8 v01 = *(const short8*)(p0 + 8);
                    short8 v02 = *(const short8*)(p0 + 16);
                    short8 v03 = *(const short8*)(p0 + 24);
                    short8 v10 = *(const short8*)(p1);
                    short8 v11 = *(const short8*)(p1 + 8);
                    short8 v12 = *(const short8*)(p1 + 16);
                    short8 v13 = *(const short8*)(p1 + 24);
#pragma unroll
                    for (int j = 0; j < 8; j++) {
                        a[j]      += bf2f((unsigned short)v00[j]) + bf2f((unsigned short)v10[j]);
                        a[8 + j]  += bf2f((unsigned short)v01[j]) + bf2f((unsigned short)v11[j]);
                        a[16 + j] += bf2f((unsigned short)v02[j]) + bf2f((unsigned short)v12[j]);
                        a[24 + j] += bf2f((unsigned short)v03[j]) + bf2f((unsigned short)v13[j]);
                    }
                }
                if (i < end) {
                    int s0 = ss[i];
                    const unsigned short* p0 = slab + (size_t)s0 * SLICE_COLS;
#pragma unroll
                    for (int g = 0; g < 4; g++) {
                        short8 v = *(const short8*)(p0 + g * 8);
#pragma unroll
                        for (int j = 0; j < 8; j++) a[g * 8 + j] += bf2f((unsigned short)v[j]);
                    }
                }
                // quad combine
#pragma unroll
                for (int j = 0; j < 32; j++) a[j] += __shfl_xor(a[j], 1);
#pragma unroll
                for (int j = 0; j < 32; j++) a[j] += __shfl_xor(a[j], 2);
                int d = end - beg;
                float inv = (d > 0) ? 1.0f / (float)d : 0.f;
                short8 o;
#pragma unroll
                for (int j = 0; j < 8; j++) o[j] = (short)f2bf(a[q * 8 + j] * inv);
                nt_store8(o, xm + (size_t)node * DIN + s * SLICE_COLS + q * 8);
            }
        }
    }
}

// ---------------- bf16 MFMA GEMM: out = xm @ W + b (f32), deg==0 rows -> 0 ----
__global__ __launch_bounds__(256) void gemm_mfma_kernel(const unsigned short* __restrict__ xm,
                                                        const unsigned short* __restrict__ Wt,
                                                        const float* __restrict__ b,
                                                        const int* __restrict__ deg,
                                                        float* __restrict__ out) {
    __shared__ unsigned short As[128 * 32];  // [row][k], 8 KB
    __shared__ unsigned short Bs[128 * 32];  // [col][k], 8 KB
    int tid = threadIdx.x;
    int bm = blockIdx.x >> 1;
    int bn = blockIdx.x & 1;
    int row0 = bm * 128, col0 = bn * 128;
    int wave = tid >> 6, lane = tid & 63;
    int wr = wave >> 1, wc = wave & 1;
    int l15 = lane & 15, kgrp = lane >> 4;

    floatx4 acc[4][4];
#pragma unroll
    for (int m = 0; m < 4; m++)
#pragma unroll
        for (int n = 0; n < 4; n++) acc[m][n] = (floatx4){0.f, 0.f, 0.f, 0.f};

    int srow = tid >> 2;
    int kchunk = (tid & 3) * 8;

    for (int kc = 0; kc < DIN; kc += 32) {
#pragma unroll
        for (int i = 0; i < 2; i++) {
            int row = i * 64 + srow;
            int ga_row = row0 + row; if (ga_row >= NN) ga_row = NN - 1;
            gload_lds16(xm + (size_t)ga_row * DIN + kc + kchunk,
                        (char*)As + i * 4096 + wave * 1024);
            gload_lds16(Wt + (size_t)(col0 + row) * DIN + kc + kchunk,
                        (char*)Bs + i * 4096 + wave * 1024);
        }
        __syncthreads();

        short8 af[4], bf[4];
#pragma unroll
        for (int m = 0; m < 4; m++)
            af[m] = *(const short8*)&As[(wr * 64 + m * 16 + l15) * 32 + kgrp * 8];
#pragma unroll
        for (int n = 0; n < 4; n++)
            bf[n] = *(const short8*)&Bs[(wc * 64 + n * 16 + l15) * 32 + kgrp * 8];
#pragma unroll
        for (int m = 0; m < 4; m++)
#pragma unroll
            for (int n = 0; n < 4; n++)
                acc[m][n] = __builtin_amdgcn_mfma_f32_16x16x32_bf16(af[m], bf[n], acc[m][n], 0, 0, 0);
        __syncthreads();
    }

    float bias[4];
#pragma unroll
    for (int n = 0; n < 4; n++) bias[n] = b[col0 + wc * 64 + n * 16 + l15];

#pragma unroll
    for (int m = 0; m < 4; m++) {
#pragma unroll
        for (int r = 0; r < 4; r++) {
            int row = row0 + wr * 64 + m * 16 + kgrp * 4 + r;
            if (row < NN) {
                int dg = deg[row];
#pragma unroll
                for (int n = 0; n < 4; n++) {
                    int col = col0 + wc * 64 + n * 16 + l15;
                    out[(size_t)row * DOUT + col] = (dg > 0) ? acc[m][n][r] + bias[n] : 0.f;
                }
            }
        }
    }
}

extern "C" void kernel_launch(void* const* d_in, const int* in_sizes, int n_in,
                              void* d_out, int out_size, void* d_ws, size_t ws_size,
                              hipStream_t stream) {
    const float* x = (const float*)d_in[0];
    const float* W = (const float*)d_in[1];
    const float* b = (const float*)d_in[2];
    const int* esrc = (const int*)d_in[3];
    const int* edst = (const int*)d_in[4];
    float* out = (float*)d_out;

    char* ws = (char*)d_ws;
    size_t off = 0;
    unsigned short* xbs = (unsigned short*)(ws + off); off += (size_t)NN * DIN * 2;  // 25.6 MB (8 slabs)
    unsigned short* xm = (unsigned short*)(ws + off); off += (size_t)NN * DIN * 2;   // 25.6 MB
    unsigned short* Wt = (unsigned short*)(ws + off); off += (size_t)DIN * DOUT * 2; // 128 KB
    int* deg = (int*)(ws + off); off += (size_t)NN * sizeof(int);
    int* cursor = (int*)(ws + off); off += (size_t)NN * sizeof(int);  // contiguous with deg
    int* sctr = (int*)(ws + off); off += 8 * sizeof(int);             // contiguous with cursor
    int* offs = (int*)(ws + off); off += (size_t)(NN + 1) * sizeof(int);
    off = (off + 15) & ~(size_t)15;
    int* sorted_src = (int*)(ws + off); off += (size_t)NE * sizeof(int);

    zero_ints_kernel<<<(2 * NN + 8 + 255) / 256, 256, 0, stream>>>(deg, 2 * NN + 8);
    prep_kernel<<<4352, 256, 0, stream>>>(x, W, xbs, Wt, edst, deg);
    scan_kernel<<<1, 1024, 0, stream>>>(deg, offs);
    scatter_kernel<<<2048, 256, 0, stream>>>(esrc, edst, offs, cursor, sorted_src);
    slice_mean_kernel<<<NSLICE * NCHUNK, 256, 0, stream>>>(xbs, offs, sorted_src, sctr, xm);
    gemm_mfma_kernel<<<391 * 2, 256, 0, stream>>>(xm, Wt, b, deg, out);
}

// Round 8
// 264.310 us; speedup vs baseline: 3.2204x; 3.2204x over previous
//
#include <hip/hip_runtime.h>

#define NN 50000
#define NE 800000
#define DIN 256
#define DOUT 256
#define NSLICE 8
#define SLICE_COLS 32
#define CHUNK_NODES 64
#define NCHUNK ((NN + CHUNK_NODES - 1) / CHUNK_NODES)  // 782

typedef __attribute__((ext_vector_type(8))) short short8;
typedef __attribute__((ext_vector_type(4))) float floatx4;

static __device__ __forceinline__ unsigned short f2bf(float f) {
    unsigned int u = __float_as_uint(f);
    unsigned int r = (u + 0x7fffu + ((u >> 16) & 1u)) >> 16;
    return (unsigned short)r;
}
static __device__ __forceinline__ float bf2f(unsigned short h) {
    return __uint_as_float(((unsigned int)h) << 16);
}

static __device__ __forceinline__ void gload_lds16(const void* g, void* l) {
    __builtin_amdgcn_global_load_lds(
        (const __attribute__((address_space(1))) unsigned int*)g,
        (__attribute__((address_space(3))) unsigned int*)l, 16, 0, 0);
}

static __device__ __forceinline__ void nt_store8(short8 v, unsigned short* p) {
    __builtin_nontemporal_store(v, (short8*)p);
}

// ---------------- utility: zero ints ----------------
__global__ void zero_ints_kernel(int* __restrict__ p, int n) {
    int i = blockIdx.x * blockDim.x + threadIdx.x;
    if (i < n) p[i] = 0;
}

// ---- fused prep: cast x -> SLICED bf16 slabs, cast+transpose W, degree hist ----
// xbs layout: slab s (cols [32s,32s+32)) is contiguous: xbs[s*NN*32 + node*32 + c]
__global__ __launch_bounds__(256) void prep_kernel(const float* __restrict__ x,
                                                   const float* __restrict__ W,
                                                   unsigned short* __restrict__ xbs,
                                                   unsigned short* __restrict__ Wt,
                                                   const int* __restrict__ edst,
                                                   int* __restrict__ deg) {
    int bid = blockIdx.x;
    if (bid < 2048) {
        const int total = NN * 32;  // 8-col groups
        int stride = 2048 * 256;
        for (int i = bid * 256 + threadIdx.x; i < total; i += stride) {
            int node = i >> 5, cg = i & 31;
            const float* src = x + (size_t)node * DIN + cg * 8;
            float4 v0 = *(const float4*)(src);
            float4 v1 = *(const float4*)(src + 4);
            short8 o;
            o[0] = (short)f2bf(v0.x); o[1] = (short)f2bf(v0.y);
            o[2] = (short)f2bf(v0.z); o[3] = (short)f2bf(v0.w);
            o[4] = (short)f2bf(v1.x); o[5] = (short)f2bf(v1.y);
            o[6] = (short)f2bf(v1.z); o[7] = (short)f2bf(v1.w);
            int s = cg >> 2;
            int c8 = (cg & 3) * 8;
            nt_store8(o, xbs + (size_t)s * NN * SLICE_COLS + (size_t)node * SLICE_COLS + c8);
        }
    } else if (bid < 2304) {
        int n = bid - 2048;
        int k = threadIdx.x;
        Wt[(size_t)n * DIN + k] = f2bf(W[(size_t)k * DOUT + n]);
    } else {
        int stride = 2048 * 256;
        for (int e = (bid - 2304) * 256 + threadIdx.x; e < NE; e += stride)
            atomicAdd(&deg[edst[e]], 1);
    }
}

// ---------------- single-block exclusive scan over 50000 ints ----------------
__global__ __launch_bounds__(1024) void scan_kernel(const int* __restrict__ deg,
                                                    int* __restrict__ offs) {
    __shared__ int bufA[1024];
    __shared__ int bufB[1024];
    int t = threadIdx.x;
    const int chunk = (NN + 1023) / 1024;  // 49
    int begin = t * chunk;
    int end = begin + chunk;
    if (begin > NN) begin = NN;
    if (end > NN) end = NN;
    int s = 0;
    for (int i = begin; i < end; i++) s += deg[i];
    bufA[t] = s;
    __syncthreads();
    int* src = bufA;
    int* dst = bufB;
    for (int off = 1; off < 1024; off <<= 1) {
        dst[t] = src[t] + ((t >= off) ? src[t - off] : 0);
        __syncthreads();
        int* tmp = src; src = dst; dst = tmp;
    }
    int run = (t == 0) ? 0 : src[t - 1];
    for (int i = begin; i < end; i++) { offs[i] = run; run += deg[i]; }
    if (t == 1023) offs[NN] = src[1023];  // == NE
}

// ---------------- scatter edges into CSR (by destination) ----------------
__global__ void scatter_kernel(const int* __restrict__ edge_src,
                               const int* __restrict__ edge_dst,
                               const int* __restrict__ offs,
                               int* __restrict__ cursor,
                               int* __restrict__ sorted_src) {
    int stride = gridDim.x * blockDim.x;
    for (int e = blockIdx.x * blockDim.x + threadIdx.x; e < NE; e += stride) {
        int d = edge_dst[e];
        int pos = offs[d] + atomicAdd(&cursor[d], 1);
        sorted_src[pos] = edge_src[e];
    }
}

// ---------------- XCD-sliced per-node mean (STATIC mapping) ----------------
// slice = blockIdx & 7 (round-robin dispatch lands slice k's blocks on XCD k,
// so the 3.2 MB slab stays L2-resident); chunk = blockIdx >> 3.
// Per chunk: 64 nodes; 4 lanes/node; lane q takes edges beg+q, +4, ...;
// accumulates all 32 slab cols in regs; quad-combine via shfl_xor(1,2);
// lane q writes cols [q*8,q*8+8) of the slice (non-temporal).
// No atomics, no barriers (R7's work-stealing was the poison: hot-line
// device-scope atomics ping-ponging across XCD L2s).
__global__ __launch_bounds__(256) void slice_mean_kernel(const unsigned short* __restrict__ xbs,
                                                         const int* __restrict__ offs,
                                                         const int* __restrict__ ss,
                                                         unsigned short* __restrict__ xm) {
    int s = blockIdx.x & 7;
    int chunk = blockIdx.x >> 3;
    int tid = threadIdx.x;
    int nq = tid >> 2;  // node 0..63 within chunk
    int q = tid & 3;    // quad lane

    const unsigned short* slab = xbs + (size_t)s * NN * SLICE_COLS;
    int node = chunk * CHUNK_NODES + nq;
    if (node >= NN) return;

    int beg = offs[node], end = offs[node + 1];
    float a[32];
#pragma unroll
    for (int j = 0; j < 32; j++) a[j] = 0.f;
    int i = beg + q;
    for (; i + 4 < end; i += 8) {  // 2 edges per iter for this lane
        int s0 = ss[i], s1 = ss[i + 4];
        const unsigned short* p0 = slab + (size_t)s0 * SLICE_COLS;
        const unsigned short* p1 = slab + (size_t)s1 * SLICE_COLS;
        short8 v00 = *(const short8*)(p0);
        short8 v01 = *(const short8*)(p0 + 8);
        short8 v02 = *(const short8*)(p0 + 16);
        short8 v03 = *(const short8*)(p0 + 24);
        short8 v10 = *(const short8*)(p1);
        short8 v11 = *(const short8*)(p1 + 8);
        short8 v12 = *(const short8*)(p1 + 16);
        short8 v13 = *(const short8*)(p1 + 24);
#pragma unroll
        for (int j = 0; j < 8; j++) {
            a[j]      += bf2f((unsigned short)v00[j]) + bf2f((unsigned short)v10[j]);
            a[8 + j]  += bf2f((unsigned short)v01[j]) + bf2f((unsigned short)v11[j]);
            a[16 + j] += bf2f((unsigned short)v02[j]) + bf2f((unsigned short)v12[j]);
            a[24 + j] += bf2f((unsigned short)v03[j]) + bf2f((unsigned short)v13[j]);
        }
    }
    if (i < end) {
        int s0 = ss[i];
        const unsigned short* p0 = slab + (size_t)s0 * SLICE_COLS;
#pragma unroll
        for (int g = 0; g < 4; g++) {
            short8 v = *(const short8*)(p0 + g * 8);
#pragma unroll
            for (int j = 0; j < 8; j++) a[g * 8 + j] += bf2f((unsigned short)v[j]);
        }
    }
    // quad combine
#pragma unroll
    for (int j = 0; j < 32; j++) a[j] += __shfl_xor(a[j], 1);
#pragma unroll
    for (int j = 0; j < 32; j++) a[j] += __shfl_xor(a[j], 2);
    int d = end - beg;
    float inv = (d > 0) ? 1.0f / (float)d : 0.f;
    short8 o;
#pragma unroll
    for (int j = 0; j < 8; j++) o[j] = (short)f2bf(a[q * 8 + j] * inv);
    nt_store8(o, xm + (size_t)node * DIN + s * SLICE_COLS + q * 8);
}

// ---------------- bf16 MFMA GEMM: out = xm @ W + b (f32), deg==0 rows -> 0 ----
__global__ __launch_bounds__(256) void gemm_mfma_kernel(const unsigned short* __restrict__ xm,
                                                        const unsigned short* __restrict__ Wt,
                                                        const float* __restrict__ b,
                                                        const int* __restrict__ deg,
                                                        float* __restrict__ out) {
    __shared__ unsigned short As[128 * 32];  // [row][k], 8 KB
    __shared__ unsigned short Bs[128 * 32];  // [col][k], 8 KB
    int tid = threadIdx.x;
    int bm = blockIdx.x >> 1;
    int bn = blockIdx.x & 1;
    int row0 = bm * 128, col0 = bn * 128;
    int wave = tid >> 6, lane = tid & 63;
    int wr = wave >> 1, wc = wave & 1;
    int l15 = lane & 15, kgrp = lane >> 4;

    floatx4 acc[4][4];
#pragma unroll
    for (int m = 0; m < 4; m++)
#pragma unroll
        for (int n = 0; n < 4; n++) acc[m][n] = (floatx4){0.f, 0.f, 0.f, 0.f};

    int srow = tid >> 2;
    int kchunk = (tid & 3) * 8;

    for (int kc = 0; kc < DIN; kc += 32) {
#pragma unroll
        for (int i = 0; i < 2; i++) {
            int row = i * 64 + srow;
            int ga_row = row0 + row; if (ga_row >= NN) ga_row = NN - 1;
            gload_lds16(xm + (size_t)ga_row * DIN + kc + kchunk,
                        (char*)As + i * 4096 + wave * 1024);
            gload_lds16(Wt + (size_t)(col0 + row) * DIN + kc + kchunk,
                        (char*)Bs + i * 4096 + wave * 1024);
        }
        __syncthreads();

        short8 af[4], bf[4];
#pragma unroll
        for (int m = 0; m < 4; m++)
            af[m] = *(const short8*)&As[(wr * 64 + m * 16 + l15) * 32 + kgrp * 8];
#pragma unroll
        for (int n = 0; n < 4; n++)
            bf[n] = *(const short8*)&Bs[(wc * 64 + n * 16 + l15) * 32 + kgrp * 8];
#pragma unroll
        for (int m = 0; m < 4; m++)
#pragma unroll
            for (int n = 0; n < 4; n++)
                acc[m][n] = __builtin_amdgcn_mfma_f32_16x16x32_bf16(af[m], bf[n], acc[m][n], 0, 0, 0);
        __syncthreads();
    }

    float bias[4];
#pragma unroll
    for (int n = 0; n < 4; n++) bias[n] = b[col0 + wc * 64 + n * 16 + l15];

#pragma unroll
    for (int m = 0; m < 4; m++) {
#pragma unroll
        for (int r = 0; r < 4; r++) {
            int row = row0 + wr * 64 + m * 16 + kgrp * 4 + r;
            if (row < NN) {
                int dg = deg[row];
#pragma unroll
                for (int n = 0; n < 4; n++) {
                    int col = col0 + wc * 64 + n * 16 + l15;
                    out[(size_t)row * DOUT + col] = (dg > 0) ? acc[m][n][r] + bias[n] : 0.f;
                }
            }
        }
    }
}

extern "C" void kernel_launch(void* const* d_in, const int* in_sizes, int n_in,
                              void* d_out, int out_size, void* d_ws, size_t ws_size,
                              hipStream_t stream) {
    const float* x = (const float*)d_in[0];
    const float* W = (const float*)d_in[1];
    const float* b = (const float*)d_in[2];
    const int* esrc = (const int*)d_in[3];
    const int* edst = (const int*)d_in[4];
    float* out = (float*)d_out;

    char* ws = (char*)d_ws;
    size_t off = 0;
    unsigned short* xbs = (unsigned short*)(ws + off); off += (size_t)NN * DIN * 2;  // 25.6 MB (8 slabs)
    unsigned short* xm = (unsigned short*)(ws + off); off += (size_t)NN * DIN * 2;   // 25.6 MB
    unsigned short* Wt = (unsigned short*)(ws + off); off += (size_t)DIN * DOUT * 2; // 128 KB
    int* deg = (int*)(ws + off); off += (size_t)NN * sizeof(int);
    int* cursor = (int*)(ws + off); off += (size_t)NN * sizeof(int);  // contiguous with deg
    int* offs = (int*)(ws + off); off += (size_t)(NN + 1) * sizeof(int);
    off = (off + 15) & ~(size_t)15;
    int* sorted_src = (int*)(ws + off); off += (size_t)NE * sizeof(int);

    zero_ints_kernel<<<(2 * NN + 255) / 256, 256, 0, stream>>>(deg, 2 * NN);
    prep_kernel<<<4352, 256, 0, stream>>>(x, W, xbs, Wt, edst, deg);
    scan_kernel<<<1, 1024, 0, stream>>>(deg, offs);
    scatter_kernel<<<2048, 256, 0, stream>>>(esrc, edst, offs, cursor, sorted_src);
    slice_mean_kernel<<<NCHUNK * NSLICE, 256, 0, stream>>>(xbs, offs, sorted_src, xm);
    gemm_mfma_kernel<<<391 * 2, 256, 0, stream>>>(xm, Wt, b, deg, out);
}

// Round 9
// 200.790 us; speedup vs baseline: 4.2391x; 1.3163x over previous
//
#include <hip/hip_runtime.h>

#define NN 50000
#define NE 800000
#define DIN 256
#define DOUT 256
#define NB 196  // ceil(NN/256) for 3-phase scan
#define NSLICE 8
#define SLICE_COLS 32
#define CHUNK_NODES 64
#define NCHUNK ((NN + CHUNK_NODES - 1) / CHUNK_NODES)  // 782
#define BATCH 4
#define NBATCH ((NCHUNK + BATCH - 1) / BATCH)  // 196
#define QPAD 32  // ints; 128B separation between queue counters

typedef __attribute__((ext_vector_type(8))) short short8;
typedef __attribute__((ext_vector_type(4))) float floatx4;

static __device__ __forceinline__ unsigned short f2bf(float f) {
    unsigned int u = __float_as_uint(f);
    unsigned int r = (u + 0x7fffu + ((u >> 16) & 1u)) >> 16;
    return (unsigned short)r;
}
static __device__ __forceinline__ float bf2f(unsigned short h) {
    return __uint_as_float(((unsigned int)h) << 16);
}

static __device__ __forceinline__ void gload_lds16(const void* g, void* l) {
    __builtin_amdgcn_global_load_lds(
        (const __attribute__((address_space(1))) unsigned int*)g,
        (__attribute__((address_space(3))) unsigned int*)l, 16, 0, 0);
}

static __device__ __forceinline__ void nt_store8(short8 v, unsigned short* p) {
    __builtin_nontemporal_store(v, (short8*)p);
}

// ---------------- utility: zero ints ----------------
__global__ void zero_ints_kernel(int* __restrict__ p, int n) {
    int i = blockIdx.x * blockDim.x + threadIdx.x;
    if (i < n) p[i] = 0;
}

// ---- fused prep: cast x -> SLICED bf16 slabs (slab-major, coalesced writes),
//      cast+transpose W, degree hist ----
// xbs: slab s (cols [32s,32s+32)) contiguous: xbs[s*NN*32 + node*32 + c]
__global__ __launch_bounds__(256) void prep_kernel(const float* __restrict__ x,
                                                   const float* __restrict__ W,
                                                   unsigned short* __restrict__ xbs,
                                                   unsigned short* __restrict__ Wt,
                                                   const int* __restrict__ edst,
                                                   int* __restrict__ deg) {
    int bid = blockIdx.x;
    if (bid < 2048) {
        const int total = NSLICE * NN * 4;  // 16B units, slab-major
        int stride = 2048 * 256;
        for (int i = bid * 256 + threadIdx.x; i < total; i += stride) {
            int s = i / (NN * 4);
            int rem = i - s * (NN * 4);
            int node = rem >> 2, g = rem & 3;
            const float* src = x + (size_t)node * DIN + s * SLICE_COLS + g * 8;
            float4 v0 = *(const float4*)(src);
            float4 v1 = *(const float4*)(src + 4);
            short8 o;
            o[0] = (short)f2bf(v0.x); o[1] = (short)f2bf(v0.y);
            o[2] = (short)f2bf(v0.z); o[3] = (short)f2bf(v0.w);
            o[4] = (short)f2bf(v1.x); o[5] = (short)f2bf(v1.y);
            o[6] = (short)f2bf(v1.z); o[7] = (short)f2bf(v1.w);
            nt_store8(o, xbs + (size_t)i * 8);  // == s*NN*32 + node*32 + g*8
        }
    } else if (bid < 2304) {
        int n = bid - 2048;
        int k = threadIdx.x;
        Wt[(size_t)n * DIN + k] = f2bf(W[(size_t)k * DOUT + n]);
    } else {
        int stride = 2048 * 256;
        for (int e = (bid - 2304) * 256 + threadIdx.x; e < NE; e += stride)
            atomicAdd(&deg[edst[e]], 1);
    }
}

// ---------------- 3-phase scan: block sums -> base scan -> final ----------------
__global__ __launch_bounds__(256) void bsum_kernel(const int* __restrict__ deg,
                                                   int* __restrict__ bsum) {
    __shared__ int s[256];
    int i = blockIdx.x * 256 + threadIdx.x;
    s[threadIdx.x] = (i < NN) ? deg[i] : 0;
    __syncthreads();
    for (int off = 128; off > 0; off >>= 1) {
        if (threadIdx.x < off) s[threadIdx.x] += s[threadIdx.x + off];
        __syncthreads();
    }
    if (threadIdx.x == 0) bsum[blockIdx.x] = s[0];
}

__global__ __launch_bounds__(256) void bbase_kernel(const int* __restrict__ bsum,
                                                    int* __restrict__ bbase,
                                                    int* __restrict__ offs) {
    __shared__ int a[256], c[256];
    int t = threadIdx.x;
    int v = (t < NB) ? bsum[t] : 0;
    a[t] = v;
    __syncthreads();
    int* src = a;
    int* dst = c;
    for (int off = 1; off < 256; off <<= 1) {
        dst[t] = src[t] + ((t >= off) ? src[t - off] : 0);
        __syncthreads();
        int* tm = src; src = dst; dst = tm;
    }
    if (t < NB) bbase[t] = src[t] - v;  // exclusive
    if (t == 0) offs[NN] = NE;
}

__global__ __launch_bounds__(256) void scanf_kernel(const int* __restrict__ deg,
                                                    const int* __restrict__ bbase,
                                                    int* __restrict__ offs) {
    __shared__ int a[256], c[256];
    int t = threadIdx.x;
    int i = blockIdx.x * 256 + t;
    int v = (i < NN) ? deg[i] : 0;
    a[t] = v;
    __syncthreads();
    int* src = a;
    int* dst = c;
    for (int off = 1; off < 256; off <<= 1) {
        dst[t] = src[t] + ((t >= off) ? src[t - off] : 0);
        __syncthreads();
        int* tm = src; src = dst; dst = tm;
    }
    if (i < NN) offs[i] = bbase[blockIdx.x] + src[t] - v;  // exclusive + base
}

// ---------------- scatter edges into CSR (by destination) ----------------
__global__ void scatter_kernel(const int* __restrict__ edge_src,
                               const int* __restrict__ edge_dst,
                               const int* __restrict__ offs,
                               int* __restrict__ cursor,
                               int* __restrict__ sorted_src) {
    int stride = gridDim.x * blockDim.x;
    for (int e = blockIdx.x * blockDim.x + threadIdx.x; e < NE; e += stride) {
        int d = edge_dst[e];
        int pos = offs[d] + atomicAdd(&cursor[d], 1);
        sorted_src[pos] = edge_src[e];
    }
}

// ---------------- XCD-sliced per-node mean, hw-XCD slice + batched claim ------
// slice chosen by the block's REAL XCD id (s_getreg HW_REG_XCC_ID) -> the
// 3.2 MB slab is L2-resident on that XCD regardless of dispatch policy
// (R7 proved layout: FETCH 174->31 MB; R7's cost was its scheduler).
// Scheduling: ONE batched claim per block (batch = 4 chunks = 256 nodes) on a
// per-XCD counter padded to its own cacheline (XCD-local atomic), fallback
// probe chain over other queues guarantees full coverage under any mapping.
__global__ __launch_bounds__(256) void slice_mean_kernel(const unsigned short* __restrict__ xbs,
                                                         const int* __restrict__ offs,
                                                         const int* __restrict__ ss,
                                                         int* __restrict__ qctr,
                                                         unsigned short* __restrict__ xm) {
    __shared__ int sh;
    int xcd;
    asm("s_getreg_b32 %0, hwreg(HW_REG_XCC_ID, 0, 32)" : "=s"(xcd));
    xcd &= 7;
    int tid = threadIdx.x;
    if (tid == 0) {
        int found = -1;
        for (int t = 0; t < NSLICE; t++) {
            int q = (xcd + t) & 7;
            int c = atomicAdd(&qctr[q * QPAD], 1);
            if (c < NBATCH) { found = q * NBATCH + c; break; }
        }
        sh = found;
    }
    __syncthreads();
    int f = sh;
    if (f < 0) return;
    int s = f / NBATCH;
    int batch = f % NBATCH;

    int nq = tid >> 2;  // node 0..63 within chunk
    int q = tid & 3;    // quad lane
    const unsigned short* slab = xbs + (size_t)s * NN * SLICE_COLS;

    for (int ci = 0; ci < BATCH; ci++) {
        int chunk = batch * BATCH + ci;
        if (chunk >= NCHUNK) break;
        int node = chunk * CHUNK_NODES + nq;
        if (node >= NN) continue;

        int beg = offs[node], end = offs[node + 1];
        float a[32];
#pragma unroll
        for (int j = 0; j < 32; j++) a[j] = 0.f;
        int i = beg + q;
        for (; i + 4 < end; i += 8) {  // 2 edges per iter for this lane
            int s0 = ss[i], s1 = ss[i + 4];
            const unsigned short* p0 = slab + (size_t)s0 * SLICE_COLS;
            const unsigned short* p1 = slab + (size_t)s1 * SLICE_COLS;
            short8 v00 = *(const short8*)(p0);
            short8 v01 = *(const short8*)(p0 + 8);
            short8 v02 = *(const short8*)(p0 + 16);
            short8 v03 = *(const short8*)(p0 + 24);
            short8 v10 = *(const short8*)(p1);
            short8 v11 = *(const short8*)(p1 + 8);
            short8 v12 = *(const short8*)(p1 + 16);
            short8 v13 = *(const short8*)(p1 + 24);
#pragma unroll
            for (int j = 0; j < 8; j++) {
                a[j]      += bf2f((unsigned short)v00[j]) + bf2f((unsigned short)v10[j]);
                a[8 + j]  += bf2f((unsigned short)v01[j]) + bf2f((unsigned short)v11[j]);
                a[16 + j] += bf2f((unsigned short)v02[j]) + bf2f((unsigned short)v12[j]);
                a[24 + j] += bf2f((unsigned short)v03[j]) + bf2f((unsigned short)v13[j]);
            }
        }
        if (i < end) {
            int s0 = ss[i];
            const unsigned short* p0 = slab + (size_t)s0 * SLICE_COLS;
#pragma unroll
            for (int g = 0; g < 4; g++) {
                short8 v = *(const short8*)(p0 + g * 8);
#pragma unroll
                for (int j = 0; j < 8; j++) a[g * 8 + j] += bf2f((unsigned short)v[j]);
            }
        }
        // quad combine
#pragma unroll
        for (int j = 0; j < 32; j++) a[j] += __shfl_xor(a[j], 1);
#pragma unroll
        for (int j = 0; j < 32; j++) a[j] += __shfl_xor(a[j], 2);
        int d = end - beg;
        float inv = (d > 0) ? 1.0f / (float)d : 0.f;
        short8 o;
#pragma unroll
        for (int j = 0; j < 8; j++) o[j] = (short)f2bf(a[q * 8 + j] * inv);
        nt_store8(o, xm + (size_t)node * DIN + s * SLICE_COLS + q * 8);
    }
}

// ---------------- bf16 MFMA GEMM: out = xm @ W + b (f32), deg==0 rows -> 0 ----
__global__ __launch_bounds__(256) void gemm_mfma_kernel(const unsigned short* __restrict__ xm,
                                                        const unsigned short* __restrict__ Wt,
                                                        const float* __restrict__ b,
                                                        const int* __restrict__ deg,
                                                        float* __restrict__ out) {
    __shared__ unsigned short As[128 * 32];  // [row][k], 8 KB
    __shared__ unsigned short Bs[128 * 32];  // [col][k], 8 KB
    int tid = threadIdx.x;
    int bm = blockIdx.x >> 1;
    int bn = blockIdx.x & 1;
    int row0 = bm * 128, col0 = bn * 128;
    int wave = tid >> 6, lane = tid & 63;
    int wr = wave >> 1, wc = wave & 1;
    int l15 = lane & 15, kgrp = lane >> 4;

    floatx4 acc[4][4];
#pragma unroll
    for (int m = 0; m < 4; m++)
#pragma unroll
        for (int n = 0; n < 4; n++) acc[m][n] = (floatx4){0.f, 0.f, 0.f, 0.f};

    int srow = tid >> 2;
    int kchunk = (tid & 3) * 8;

    for (int kc = 0; kc < DIN; kc += 32) {
#pragma unroll
        for (int i = 0; i < 2; i++) {
            int row = i * 64 + srow;
            int ga_row = row0 + row; if (ga_row >= NN) ga_row = NN - 1;
            gload_lds16(xm + (size_t)ga_row * DIN + kc + kchunk,
                        (char*)As + i * 4096 + wave * 1024);
            gload_lds16(Wt + (size_t)(col0 + row) * DIN + kc + kchunk,
                        (char*)Bs + i * 4096 + wave * 1024);
        }
        __syncthreads();

        short8 af[4], bf[4];
#pragma unroll
        for (int m = 0; m < 4; m++)
            af[m] = *(const short8*)&As[(wr * 64 + m * 16 + l15) * 32 + kgrp * 8];
#pragma unroll
        for (int n = 0; n < 4; n++)
            bf[n] = *(const short8*)&Bs[(wc * 64 + n * 16 + l15) * 32 + kgrp * 8];
#pragma unroll
        for (int m = 0; m < 4; m++)
#pragma unroll
            for (int n = 0; n < 4; n++)
                acc[m][n] = __builtin_amdgcn_mfma_f32_16x16x32_bf16(af[m], bf[n], acc[m][n], 0, 0, 0);
        __syncthreads();
    }

    float bias[4];
#pragma unroll
    for (int n = 0; n < 4; n++) bias[n] = b[col0 + wc * 64 + n * 16 + l15];

#pragma unroll
    for (int m = 0; m < 4; m++) {
#pragma unroll
        for (int r = 0; r < 4; r++) {
            int row = row0 + wr * 64 + m * 16 + kgrp * 4 + r;
            if (row < NN) {
                int dg = deg[row];
#pragma unroll
                for (int n = 0; n < 4; n++) {
                    int col = col0 + wc * 64 + n * 16 + l15;
                    out[(size_t)row * DOUT + col] = (dg > 0) ? acc[m][n][r] + bias[n] : 0.f;
                }
            }
        }
    }
}

extern "C" void kernel_launch(void* const* d_in, const int* in_sizes, int n_in,
                              void* d_out, int out_size, void* d_ws, size_t ws_size,
                              hipStream_t stream) {
    const float* x = (const float*)d_in[0];
    const float* W = (const float*)d_in[1];
    const float* b = (const float*)d_in[2];
    const int* esrc = (const int*)d_in[3];
    const int* edst = (const int*)d_in[4];
    float* out = (float*)d_out;

    char* ws = (char*)d_ws;
    size_t off = 0;
    unsigned short* xbs = (unsigned short*)(ws + off); off += (size_t)NN * DIN * 2;  // 25.6 MB (8 slabs)
    unsigned short* xm = (unsigned short*)(ws + off); off += (size_t)NN * DIN * 2;   // 25.6 MB
    unsigned short* Wt = (unsigned short*)(ws + off); off += (size_t)DIN * DOUT * 2; // 128 KB
    int* deg = (int*)(ws + off); off += (size_t)NN * sizeof(int);
    int* cursor = (int*)(ws + off); off += (size_t)NN * sizeof(int);     // contiguous with deg
    int* qctr = (int*)(ws + off); off += (size_t)NSLICE * QPAD * sizeof(int);  // contiguous, padded counters
    int* offs = (int*)(ws + off); off += (size_t)(NN + 1) * sizeof(int);
    off = (off + 15) & ~(size_t)15;
    int* sorted_src = (int*)(ws + off); off += (size_t)NE * sizeof(int);
    int* bsum = (int*)(ws + off); off += 256 * sizeof(int);
    int* bbase = (int*)(ws + off); off += 256 * sizeof(int);

    const int nzero = 2 * NN + NSLICE * QPAD;  // deg + cursor + qctr
    zero_ints_kernel<<<(nzero + 255) / 256, 256, 0, stream>>>(deg, nzero);
    prep_kernel<<<4352, 256, 0, stream>>>(x, W, xbs, Wt, edst, deg);
    bsum_kernel<<<NB, 256, 0, stream>>>(deg, bsum);
    bbase_kernel<<<1, 256, 0, stream>>>(bsum, bbase, offs);
    scanf_kernel<<<NB, 256, 0, stream>>>(deg, bbase, offs);
    scatter_kernel<<<2048, 256, 0, stream>>>(esrc, edst, offs, cursor, sorted_src);
    slice_mean_kernel<<<NSLICE * NBATCH, 256, 0, stream>>>(xbs, offs, sorted_src, qctr, xm);
    gemm_mfma_kernel<<<391 * 2, 256, 0, stream>>>(xm, Wt, b, deg, out);
}

// Round 10
// 194.727 us; speedup vs baseline: 4.3711x; 1.0311x over previous
//
#include <hip/hip_runtime.h>

#define NN 50000
#define NE 800000
#define DIN 256
#define DOUT 256
#define NB 196  // ceil(NN/256) for 3-phase scan
#define NSLICE 8
#define SLICE_COLS 32
#define CHUNK_NODES 64
#define NCHUNK ((NN + CHUNK_NODES - 1) / CHUNK_NODES)  // 782 chunks per slice
#define QPAD 32  // ints; 128B separation between queue counters

typedef __attribute__((ext_vector_type(8))) short short8;
typedef __attribute__((ext_vector_type(4))) float floatx4;

static __device__ __forceinline__ unsigned short f2bf(float f) {
    unsigned int u = __float_as_uint(f);
    unsigned int r = (u + 0x7fffu + ((u >> 16) & 1u)) >> 16;
    return (unsigned short)r;
}
static __device__ __forceinline__ float bf2f(unsigned short h) {
    return __uint_as_float(((unsigned int)h) << 16);
}

static __device__ __forceinline__ void gload_lds16(const void* g, void* l) {
    __builtin_amdgcn_global_load_lds(
        (const __attribute__((address_space(1))) unsigned int*)g,
        (__attribute__((address_space(3))) unsigned int*)l, 16, 0, 0);
}

static __device__ __forceinline__ void nt_store8(short8 v, unsigned short* p) {
    __builtin_nontemporal_store(v, (short8*)p);
}

// ---------------- utility: zero ints ----------------
__global__ void zero_ints_kernel(int* __restrict__ p, int n) {
    int i = blockIdx.x * blockDim.x + threadIdx.x;
    if (i < n) p[i] = 0;
}

// ---- fused prep: cast x -> SLICED bf16 slabs (slab-major, coalesced writes),
//      cast+transpose W, degree hist ----
// xbs: slab s (cols [32s,32s+32)) contiguous: xbs[s*NN*32 + node*32 + c]
__global__ __launch_bounds__(256) void prep_kernel(const float* __restrict__ x,
                                                   const float* __restrict__ W,
                                                   unsigned short* __restrict__ xbs,
                                                   unsigned short* __restrict__ Wt,
                                                   const int* __restrict__ edst,
                                                   int* __restrict__ deg) {
    int bid = blockIdx.x;
    if (bid < 2048) {
        const int total = NSLICE * NN * 4;  // 16B units, slab-major
        int stride = 2048 * 256;
        for (int i = bid * 256 + threadIdx.x; i < total; i += stride) {
            int s = i / (NN * 4);
            int rem = i - s * (NN * 4);
            int node = rem >> 2, g = rem & 3;
            const float* src = x + (size_t)node * DIN + s * SLICE_COLS + g * 8;
            float4 v0 = *(const float4*)(src);
            float4 v1 = *(const float4*)(src + 4);
            short8 o;
            o[0] = (short)f2bf(v0.x); o[1] = (short)f2bf(v0.y);
            o[2] = (short)f2bf(v0.z); o[3] = (short)f2bf(v0.w);
            o[4] = (short)f2bf(v1.x); o[5] = (short)f2bf(v1.y);
            o[6] = (short)f2bf(v1.z); o[7] = (short)f2bf(v1.w);
            nt_store8(o, xbs + (size_t)i * 8);  // == s*NN*32 + node*32 + g*8
        }
    } else if (bid < 2304) {
        int n = bid - 2048;
        int k = threadIdx.x;
        Wt[(size_t)n * DIN + k] = f2bf(W[(size_t)k * DOUT + n]);
    } else {
        int stride = 2048 * 256;
        for (int e = (bid - 2304) * 256 + threadIdx.x; e < NE; e += stride)
            atomicAdd(&deg[edst[e]], 1);
    }
}

// ---------------- 3-phase scan: block sums -> base scan -> final ----------------
__global__ __launch_bounds__(256) void bsum_kernel(const int* __restrict__ deg,
                                                   int* __restrict__ bsum) {
    __shared__ int s[256];
    int i = blockIdx.x * 256 + threadIdx.x;
    s[threadIdx.x] = (i < NN) ? deg[i] : 0;
    __syncthreads();
    for (int off = 128; off > 0; off >>= 1) {
        if (threadIdx.x < off) s[threadIdx.x] += s[threadIdx.x + off];
        __syncthreads();
    }
    if (threadIdx.x == 0) bsum[blockIdx.x] = s[0];
}

__global__ __launch_bounds__(256) void bbase_kernel(const int* __restrict__ bsum,
                                                    int* __restrict__ bbase,
                                                    int* __restrict__ offs) {
    __shared__ int a[256], c[256];
    int t = threadIdx.x;
    int v = (t < NB) ? bsum[t] : 0;
    a[t] = v;
    __syncthreads();
    int* src = a;
    int* dst = c;
    for (int off = 1; off < 256; off <<= 1) {
        dst[t] = src[t] + ((t >= off) ? src[t - off] : 0);
        __syncthreads();
        int* tm = src; src = dst; dst = tm;
    }
    if (t < NB) bbase[t] = src[t] - v;  // exclusive
    if (t == 0) offs[NN] = NE;
}

__global__ __launch_bounds__(256) void scanf_kernel(const int* __restrict__ deg,
                                                    const int* __restrict__ bbase,
                                                    int* __restrict__ offs) {
    __shared__ int a[256], c[256];
    int t = threadIdx.x;
    int i = blockIdx.x * 256 + t;
    int v = (i < NN) ? deg[i] : 0;
    a[t] = v;
    __syncthreads();
    int* src = a;
    int* dst = c;
    for (int off = 1; off < 256; off <<= 1) {
        dst[t] = src[t] + ((t >= off) ? src[t - off] : 0);
        __syncthreads();
        int* tm = src; src = dst; dst = tm;
    }
    if (i < NN) offs[i] = bbase[blockIdx.x] + src[t] - v;  // exclusive + base
}

// ---------------- scatter edges into CSR (by destination) ----------------
__global__ void scatter_kernel(const int* __restrict__ edge_src,
                               const int* __restrict__ edge_dst,
                               const int* __restrict__ offs,
                               int* __restrict__ cursor,
                               int* __restrict__ sorted_src) {
    int stride = gridDim.x * blockDim.x;
    for (int e = blockIdx.x * blockDim.x + threadIdx.x; e < NE; e += stride) {
        int d = edge_dst[e];
        int pos = offs[d] + atomicAdd(&cursor[d], 1);
        sorted_src[pos] = edge_src[e];
    }
}

// ---------------- XCD-sliced per-node mean, hw-XCD slice + 1 claim/block ------
// slice chosen by the block's REAL XCD id (s_getreg HW_REG_XCC_ID) -> the
// 3.2 MB slab is L2-resident on that XCD regardless of dispatch policy
// (R7+R9 proved layout: FETCH 174->31 MB). BATCH=1 + grid 8*782 restores the
// TLP that R9's batching destroyed (R9: 1568 blocks, 31% occupancy,
// latency-bound at 81us). ~6.3K claims on padded XCD-local counters are
// cheap; fallback probe chain guarantees coverage under any block->XCD mix.
__global__ __launch_bounds__(256) void slice_mean_kernel(const unsigned short* __restrict__ xbs,
                                                         const int* __restrict__ offs,
                                                         const int* __restrict__ ss,
                                                         int* __restrict__ qctr,
                                                         unsigned short* __restrict__ xm) {
    __shared__ int sh;
    int xcd;
    asm("s_getreg_b32 %0, hwreg(HW_REG_XCC_ID, 0, 32)" : "=s"(xcd));
    xcd &= 7;
    int tid = threadIdx.x;
    if (tid == 0) {
        int found = -1;
        for (int t = 0; t < NSLICE; t++) {
            int q = (xcd + t) & 7;
            int c = atomicAdd(&qctr[q * QPAD], 1);
            if (c < NCHUNK) { found = q * NCHUNK + c; break; }
        }
        sh = found;
    }
    __syncthreads();
    int f = sh;
    if (f < 0) return;
    int s = f / NCHUNK;
    int chunk = f % NCHUNK;

    int nq = tid >> 2;  // node 0..63 within chunk
    int q = tid & 3;    // quad lane
    const unsigned short* slab = xbs + (size_t)s * NN * SLICE_COLS;

    int node = chunk * CHUNK_NODES + nq;
    if (node >= NN) return;

    int beg = offs[node], end = offs[node + 1];
    float a[32];
#pragma unroll
    for (int j = 0; j < 32; j++) a[j] = 0.f;
    int i = beg + q;
    for (; i + 4 < end; i += 8) {  // 2 edges per iter for this lane
        int s0 = ss[i], s1 = ss[i + 4];
        const unsigned short* p0 = slab + (size_t)s0 * SLICE_COLS;
        const unsigned short* p1 = slab + (size_t)s1 * SLICE_COLS;
        short8 v00 = *(const short8*)(p0);
        short8 v01 = *(const short8*)(p0 + 8);
        short8 v02 = *(const short8*)(p0 + 16);
        short8 v03 = *(const short8*)(p0 + 24);
        short8 v10 = *(const short8*)(p1);
        short8 v11 = *(const short8*)(p1 + 8);
        short8 v12 = *(const short8*)(p1 + 16);
        short8 v13 = *(const short8*)(p1 + 24);
#pragma unroll
        for (int j = 0; j < 8; j++) {
            a[j]      += bf2f((unsigned short)v00[j]) + bf2f((unsigned short)v10[j]);
            a[8 + j]  += bf2f((unsigned short)v01[j]) + bf2f((unsigned short)v11[j]);
            a[16 + j] += bf2f((unsigned short)v02[j]) + bf2f((unsigned short)v12[j]);
            a[24 + j] += bf2f((unsigned short)v03[j]) + bf2f((unsigned short)v13[j]);
        }
    }
    if (i < end) {
        int s0 = ss[i];
        const unsigned short* p0 = slab + (size_t)s0 * SLICE_COLS;
#pragma unroll
        for (int g = 0; g < 4; g++) {
            short8 v = *(const short8*)(p0 + g * 8);
#pragma unroll
            for (int j = 0; j < 8; j++) a[g * 8 + j] += bf2f((unsigned short)v[j]);
        }
    }
    // quad combine
#pragma unroll
    for (int j = 0; j < 32; j++) a[j] += __shfl_xor(a[j], 1);
#pragma unroll
    for (int j = 0; j < 32; j++) a[j] += __shfl_xor(a[j], 2);
    int d = end - beg;
    float inv = (d > 0) ? 1.0f / (float)d : 0.f;
    short8 o;
#pragma unroll
    for (int j = 0; j < 8; j++) o[j] = (short)f2bf(a[q * 8 + j] * inv);
    nt_store8(o, xm + (size_t)node * DIN + s * SLICE_COLS + q * 8);
}

// ---------------- bf16 MFMA GEMM: out = xm @ W + b (f32), deg==0 rows -> 0 ----
__global__ __launch_bounds__(256) void gemm_mfma_kernel(const unsigned short* __restrict__ xm,
                                                        const unsigned short* __restrict__ Wt,
                                                        const float* __restrict__ b,
                                                        const int* __restrict__ deg,
                                                        float* __restrict__ out) {
    __shared__ unsigned short As[128 * 32];  // [row][k], 8 KB
    __shared__ unsigned short Bs[128 * 32];  // [col][k], 8 KB
    int tid = threadIdx.x;
    int bm = blockIdx.x >> 1;
    int bn = blockIdx.x & 1;
    int row0 = bm * 128, col0 = bn * 128;
    int wave = tid >> 6, lane = tid & 63;
    int wr = wave >> 1, wc = wave & 1;
    int l15 = lane & 15, kgrp = lane >> 4;

    floatx4 acc[4][4];
#pragma unroll
    for (int m = 0; m < 4; m++)
#pragma unroll
        for (int n = 0; n < 4; n++) acc[m][n] = (floatx4){0.f, 0.f, 0.f, 0.f};

    int srow = tid >> 2;
    int kchunk = (tid & 3) * 8;

    for (int kc = 0; kc < DIN; kc += 32) {
#pragma unroll
        for (int i = 0; i < 2; i++) {
            int row = i * 64 + srow;
            int ga_row = row0 + row; if (ga_row >= NN) ga_row = NN - 1;
            gload_lds16(xm + (size_t)ga_row * DIN + kc + kchunk,
                        (char*)As + i * 4096 + wave * 1024);
            gload_lds16(Wt + (size_t)(col0 + row) * DIN + kc + kchunk,
                        (char*)Bs + i * 4096 + wave * 1024);
        }
        __syncthreads();

        short8 af[4], bf[4];
#pragma unroll
        for (int m = 0; m < 4; m++)
            af[m] = *(const short8*)&As[(wr * 64 + m * 16 + l15) * 32 + kgrp * 8];
#pragma unroll
        for (int n = 0; n < 4; n++)
            bf[n] = *(const short8*)&Bs[(wc * 64 + n * 16 + l15) * 32 + kgrp * 8];
#pragma unroll
        for (int m = 0; m < 4; m++)
#pragma unroll
            for (int n = 0; n < 4; n++)
                acc[m][n] = __builtin_amdgcn_mfma_f32_16x16x32_bf16(af[m], bf[n], acc[m][n], 0, 0, 0);
        __syncthreads();
    }

    float bias[4];
#pragma unroll
    for (int n = 0; n < 4; n++) bias[n] = b[col0 + wc * 64 + n * 16 + l15];

#pragma unroll
    for (int m = 0; m < 4; m++) {
#pragma unroll
        for (int r = 0; r < 4; r++) {
            int row = row0 + wr * 64 + m * 16 + kgrp * 4 + r;
            if (row < NN) {
                int dg = deg[row];
#pragma unroll
                for (int n = 0; n < 4; n++) {
                    int col = col0 + wc * 64 + n * 16 + l15;
                    out[(size_t)row * DOUT + col] = (dg > 0) ? acc[m][n][r] + bias[n] : 0.f;
                }
            }
        }
    }
}

extern "C" void kernel_launch(void* const* d_in, const int* in_sizes, int n_in,
                              void* d_out, int out_size, void* d_ws, size_t ws_size,
                              hipStream_t stream) {
    const float* x = (const float*)d_in[0];
    const float* W = (const float*)d_in[1];
    const float* b = (const float*)d_in[2];
    const int* esrc = (const int*)d_in[3];
    const int* edst = (const int*)d_in[4];
    float* out = (float*)d_out;

    char* ws = (char*)d_ws;
    size_t off = 0;
    unsigned short* xbs = (unsigned short*)(ws + off); off += (size_t)NN * DIN * 2;  // 25.6 MB (8 slabs)
    unsigned short* xm = (unsigned short*)(ws + off); off += (size_t)NN * DIN * 2;   // 25.6 MB
    unsigned short* Wt = (unsigned short*)(ws + off); off += (size_t)DIN * DOUT * 2; // 128 KB
    int* deg = (int*)(ws + off); off += (size_t)NN * sizeof(int);
    int* cursor = (int*)(ws + off); off += (size_t)NN * sizeof(int);     // contiguous with deg
    int* qctr = (int*)(ws + off); off += (size_t)NSLICE * QPAD * sizeof(int);  // contiguous, padded counters
    int* offs = (int*)(ws + off); off += (size_t)(NN + 1) * sizeof(int);
    off = (off + 15) & ~(size_t)15;
    int* sorted_src = (int*)(ws + off); off += (size_t)NE * sizeof(int);
    int* bsum = (int*)(ws + off); off += 256 * sizeof(int);
    int* bbase = (int*)(ws + off); off += 256 * sizeof(int);

    const int nzero = 2 * NN + NSLICE * QPAD;  // deg + cursor + qctr
    zero_ints_kernel<<<(nzero + 255) / 256, 256, 0, stream>>>(deg, nzero);
    prep_kernel<<<4352, 256, 0, stream>>>(x, W, xbs, Wt, edst, deg);
    bsum_kernel<<<NB, 256, 0, stream>>>(deg, bsum);
    bbase_kernel<<<1, 256, 0, stream>>>(bsum, bbase, offs);
    scanf_kernel<<<NB, 256, 0, stream>>>(deg, bbase, offs);
    scatter_kernel<<<2048, 256, 0, stream>>>(esrc, edst, offs, cursor, sorted_src);
    slice_mean_kernel<<<NSLICE * NCHUNK, 256, 0, stream>>>(xbs, offs, sorted_src, qctr, xm);
    gemm_mfma_kernel<<<391 * 2, 256, 0, stream>>>(xm, Wt, b, deg, out);
}